// Round 15
// baseline (2556.548 us; speedup 1.0000x reference)
//
#include <hip/hip_runtime.h>

typedef __attribute__((ext_vector_type(4))) float f32x4;
typedef __attribute__((ext_vector_type(8))) __bf16 bf16x8;
typedef __attribute__((ext_vector_type(4))) float f32x4v;

#define TOTALW 4096
static const size_t WTOT = 2752512ull;           // sum w^2

__device__ __forceinline__ bf16x8 cvt8(f32x4 a, f32x4 b) {
  bf16x8 r;
  r[0] = (__bf16)a.x; r[1] = (__bf16)a.y; r[2] = (__bf16)a.z; r[3] = (__bf16)a.w;
  r[4] = (__bf16)b.x; r[5] = (__bf16)b.y; r[6] = (__bf16)b.z; r[7] = (__bf16)b.w;
  return r;
}

// ---------------- pass 1: fp32 -> bf16 convert of W only (5.5 MB, ~10us) ----------------
struct WCArgs { const float* W[8]; ushort* ws; };

__global__ __launch_bounds__(256) void wconvert_kernel(WCArgs a) {
  const size_t e = ((size_t)blockIdx.x * 256 + threadIdx.x) << 3;
  if (e >= WTOT) return;
  int l = 0; size_t base = 0;
  if (e >= 16384)   { l = 1; base = 16384; }
  if (e >= 32768)   { l = 2; base = 32768; }
  if (e >= 180224)  { l = 3; base = 180224; }
  if (e >= 327680)  { l = 4; base = 327680; }
  if (e >= 737280)  { l = 5; base = 737280; }
  if (e >= 1146880) { l = 6; base = 1146880; }
  if (e >= 1949696) { l = 7; base = 1949696; }
  const float* w = a.W[0];
  if (l == 1) w = a.W[1]; if (l == 2) w = a.W[2]; if (l == 3) w = a.W[3];
  if (l == 4) w = a.W[4]; if (l == 5) w = a.W[5]; if (l == 6) w = a.W[6];
  if (l == 7) w = a.W[7];
  const float* src = w + (e - base);
  f32x4 v0 = *(const f32x4*)src;
  f32x4 v1 = *(const f32x4*)(src + 4);
  *(bf16x8*)(a.ws + e) = cvt8(v0, v1);
}

// ---------------- pass 2: fused GEMM, r14 structure + A reg-double-buffer ----------------
// Change vs r14 (one variable): A-loads for tile kt+1 issue DURING tile kt and stay
// in flight across the MFMA phase (named even/odd regs pa*/qa* — no arrays/lambdas,
// rule #20). Issue order B-first so counted vmcnt retires {A(k)} then {B(k)} while
// A(k+1) rides through. Exposed per-iter latency drops from ~HBM(A) to ~L2(B).
struct GArgs { const float* x; const ushort* Wb[8]; float* out; };

__device__ __forceinline__ void gl16(const ushort* g, ushort* l) {
  __builtin_amdgcn_global_load_lds(
      (const __attribute__((address_space(1))) void*)g,
      (__attribute__((address_space(3))) void*)l, 16, 0, 0);
}

#define VMW(n) asm volatile("s_waitcnt vmcnt(" #n ")" ::: "memory")

__global__ __launch_bounds__(512, 6) void gemm_kernel(GArgs args) {
  __shared__ __align__(16) ushort As[128 * 64];   // 16 KB (ds_write, XOR-swizzled dest)
  __shared__ __align__(16) ushort Bs[256 * 64];   // 32 KB (gl16 linear dest, src pre-XOR)

  const int tid = threadIdx.x;
  const int bid = blockIdx.x;
  const int work = (bid & 7) * 640 + (bid >> 3);   // XCD-chunked, mt-major
  const int mt = work / 20;
  const int t  = 19 - (work - mt * 20);            // heavy-first

  const int l = (t >= 1) + (t >= 2) + (t >= 4) + (t >= 6) + (t >= 9) + (t >= 12) + (t >= 16);
  const int p = l >> 1, q = l & 1;
  const int nirr = l | 1;                          // {1,1,3,3,5,5,7,7}
  const int cstart = 2 * p * p + q * nirr;
  const int w  = nirr << 7;                        // K
  const int nk = nirr << 1;                        // K-tiles of 64 (always even)
  const int sK = cstart << 7;
  const int tstart = (p + q) * (p + 1);
  const int j = t - tstart;
  const bool tail = (j == p);                      // last tile 128 wide
  const int col  = sK + j * 256;
  const ushort* __restrict__ Wbl = args.Wb[l];

  // B staging (gl16): linear LDS dest, source chunk pre-XORed (rule 21)
  const int trow = tid >> 3;                       // 0..63
  const int schunk = (tid & 7) ^ (trow & 7);
  const ushort* bSrc = Wbl + (size_t)(j * 256 + trow) * w + schunk * 8;

  // A staging (fp32 regs -> cvt -> swizzled ds_write)
  const int arow = tid >> 3;
  const int ask  = (tid & 7) << 3;
  const float* __restrict__ aSrc0 = args.x + (size_t)(mt * 128 + arow) * TOTALW + sK + ask;
  const float* __restrict__ aSrc1 = aSrc0 + (size_t)64 * TOTALW;
  ushort* aDst0 = &As[((arow     ) * 64 + ask) ^ ((arow & 7) << 3)];
  ushort* aDst1 = &As[((arow + 64) * 64 + ask) ^ ((arow & 7) << 3)];   // (arow+64)&7 == arow&7

  const int lane = tid & 63;
  const int wid  = tid >> 6;
  const int fr = lane & 15;
  const int kq = lane >> 4;

#define SHB(kt, r) gl16(bSrc + (size_t)((r) * 64) * w + (size_t)(kt) * 64, &Bs[(r) * 4096 + tid * 8])
#define ALD(n0, n1, n2, n3, k)                              \
  { n0 = *(const f32x4*)(aSrc0 + (k) * 64);                 \
    n1 = *(const f32x4*)(aSrc0 + (k) * 64 + 4);             \
    n2 = *(const f32x4*)(aSrc1 + (k) * 64);                 \
    n3 = *(const f32x4*)(aSrc1 + (k) * 64 + 4); }

  if (!tail) {
    // ---- 128x256 tile: 2x4 wave grid, wave tile 64x64 ----
    const int wr = (wid >> 2) << 6;
    const int wc = (wid & 3) << 6;
    f32x4v acc[4][4] = {};
    f32x4 pa0, pa1, pa2, pa3, qa0, qa1, qa2, qa3;

// steady state at body entry: A(k) 4 loads in flight (issued prev body, youngest).
// issue B(k) [oldest-after-A], then A(k+1); vmcnt(8) retires A(k) -> cvt+ds_write;
// vmcnt(4) retires B(k); A(k+1) stays in flight across MFMA.
#define BODYM(c0, c1, c2, c3, n0, n1, n2, n3, k)                         \
  {                                                                      \
    SHB(k, 0); SHB(k, 1); SHB(k, 2); SHB(k, 3);                          \
    __builtin_amdgcn_sched_barrier(0);                                   \
    if ((k) + 1 < nk) {                                                  \
      ALD(n0, n1, n2, n3, (k) + 1);                                      \
      __builtin_amdgcn_sched_barrier(0);                                 \
      VMW(8);                                                            \
    } else { VMW(4); }                                                   \
    *(bf16x8*)aDst0 = cvt8(c0, c1);                                      \
    *(bf16x8*)aDst1 = cvt8(c2, c3);                                      \
    __builtin_amdgcn_sched_barrier(0);                                   \
    if ((k) + 1 < nk) { VMW(4); } else { VMW(0); }                       \
    asm volatile("s_waitcnt lgkmcnt(0)" ::: "memory");                   \
    __syncthreads();                                                     \
    _Pragma("unroll")                                                    \
    for (int kk = 0; kk < 2; ++kk) {                                     \
      const int kb = kk * 32 + kq * 8;                                   \
      bf16x8 afr[4], bfr[4];                                             \
      _Pragma("unroll")                                                  \
      for (int i = 0; i < 4; ++i) {                                      \
        const int ra = wr + i * 16 + fr;                                 \
        afr[i] = *(const bf16x8*)&As[(ra * 64 + kb) ^ ((fr & 7) << 3)];  \
        const int rb = wc + i * 16 + fr;                                 \
        bfr[i] = *(const bf16x8*)&Bs[(rb * 64 + kb) ^ ((fr & 7) << 3)];  \
      }                                                                  \
      _Pragma("unroll")                                                  \
      for (int mi = 0; mi < 4; ++mi)                                     \
        _Pragma("unroll")                                                \
        for (int ni = 0; ni < 4; ++ni)                                   \
          acc[mi][ni] = __builtin_amdgcn_mfma_f32_16x16x32_bf16(afr[mi], bfr[ni], acc[mi][ni], 0, 0, 0); \
    }                                                                    \
    if ((k) + 1 < nk) __syncthreads();                                   \
  }

    ALD(pa0, pa1, pa2, pa3, 0);                     // prologue: A(0) in flight
    for (int kt = 0; kt < nk; kt += 2) {
      BODYM(pa0, pa1, pa2, pa3, qa0, qa1, qa2, qa3, kt);
      BODYM(qa0, qa1, qa2, qa3, pa0, pa1, pa2, pa3, kt + 1);
    }
#undef BODYM

    float* op = args.out + (size_t)(mt * 128 + wr + kq * 4) * TOTALW + col + wc + fr;
#pragma unroll
    for (int mi = 0; mi < 4; ++mi) {
#pragma unroll
      for (int ni = 0; ni < 4; ++ni) {
        float* pp = op + (size_t)(mi * 16) * TOTALW + ni * 16;
        pp[0 * TOTALW] = acc[mi][ni][0];
        pp[1 * TOTALW] = acc[mi][ni][1];
        pp[2 * TOTALW] = acc[mi][ni][2];
        pp[3 * TOTALW] = acc[mi][ni][3];
      }
    }
  } else {
    // ---- 128x128 tail tile: 4x2 wave grid, wave tile 32x64 ----
    const int wr = (wid >> 1) << 5;
    const int wc = (wid & 1) << 6;
    f32x4v acc[2][4] = {};
    f32x4 pa0, pa1, pa2, pa3, qa0, qa1, qa2, qa3;

#define BODYT(c0, c1, c2, c3, n0, n1, n2, n3, k)                         \
  {                                                                      \
    SHB(k, 0); SHB(k, 1);                                                \
    __builtin_amdgcn_sched_barrier(0);                                   \
    if ((k) + 1 < nk) {                                                  \
      ALD(n0, n1, n2, n3, (k) + 1);                                      \
      __builtin_amdgcn_sched_barrier(0);                                 \
      VMW(6);                                                            \
    } else { VMW(2); }                                                   \
    *(bf16x8*)aDst0 = cvt8(c0, c1);                                      \
    *(bf16x8*)aDst1 = cvt8(c2, c3);                                      \
    __builtin_amdgcn_sched_barrier(0);                                   \
    if ((k) + 1 < nk) { VMW(4); } else { VMW(0); }                       \
    asm volatile("s_waitcnt lgkmcnt(0)" ::: "memory");                   \
    __syncthreads();                                                     \
    _Pragma("unroll")                                                    \
    for (int kk = 0; kk < 2; ++kk) {                                     \
      const int kb = kk * 32 + kq * 8;                                   \
      bf16x8 afr[2], bfr[4];                                             \
      _Pragma("unroll")                                                  \
      for (int i = 0; i < 2; ++i) {                                      \
        const int ra = wr + i * 16 + fr;                                 \
        afr[i] = *(const bf16x8*)&As[(ra * 64 + kb) ^ ((fr & 7) << 3)];  \
      }                                                                  \
      _Pragma("unroll")                                                  \
      for (int i = 0; i < 4; ++i) {                                      \
        const int rb = wc + i * 16 + fr;                                 \
        bfr[i] = *(const bf16x8*)&Bs[(rb * 64 + kb) ^ ((fr & 7) << 3)];  \
      }                                                                  \
      _Pragma("unroll")                                                  \
      for (int mi = 0; mi < 2; ++mi)                                     \
        _Pragma("unroll")                                                \
        for (int ni = 0; ni < 4; ++ni)                                   \
          acc[mi][ni] = __builtin_amdgcn_mfma_f32_16x16x32_bf16(afr[mi], bfr[ni], acc[mi][ni], 0, 0, 0); \
    }                                                                    \
    if ((k) + 1 < nk) __syncthreads();                                   \
  }

    ALD(pa0, pa1, pa2, pa3, 0);
    for (int kt = 0; kt < nk; kt += 2) {
      BODYT(pa0, pa1, pa2, pa3, qa0, qa1, qa2, qa3, kt);
      BODYT(qa0, qa1, qa2, qa3, pa0, pa1, pa2, pa3, kt + 1);
    }
#undef BODYT

    float* op = args.out + (size_t)(mt * 128 + wr + kq * 4) * TOTALW + col + wc + fr;
#pragma unroll
    for (int mi = 0; mi < 2; ++mi) {
#pragma unroll
      for (int ni = 0; ni < 4; ++ni) {
        float* pp = op + (size_t)(mi * 16) * TOTALW + ni * 16;
        pp[0 * TOTALW] = acc[mi][ni][0];
        pp[1 * TOTALW] = acc[mi][ni][1];
        pp[2 * TOTALW] = acc[mi][ni][2];
        pp[3 * TOTALW] = acc[mi][ni][3];
      }
    }
  }
#undef SHB
#undef ALD
}

// ---------------- fallback (round-1 kernel, used only if ws too small) ----------------
struct FArgs { const float* x; const float* W[8]; float* out; };

__global__ __launch_bounds__(256, 2) void ielin_fb(FArgs args) {
  __shared__ __align__(16) ushort Asf[128 * 64];
  __shared__ __align__(16) ushort Bsf[128 * 64];
  const int tid = threadIdx.x;
  const int bid = blockIdx.x;
  const int work = (bid & 7) * 1024 + (bid >> 3);
  const int mt = work >> 5;
  const int c  = work & 31;
  const int l = (c >= 1) + (c >= 2) + (c >= 5) + (c >= 8) + (c >= 13) + (c >= 18) + (c >= 25);
  const int pp = l >> 1, qq = l & 1;
  const int nirr = l | 1;
  const int cstart = 2 * pp * pp + qq * nirr;
  const int w  = nirr << 7;
  const int sK = cstart << 7;
  const int noff = (c - cstart) << 7;
  const float* __restrict__ Wl = args.W[l];
  const int srow = tid >> 3;
  const int sk   = (tid & 7) << 3;
  const float* ap = args.x + (size_t)(mt * 128 + srow) * TOTALW + sK + sk;
  const float* bp = Wl + (size_t)(noff + srow) * w + sk;
  const size_t aStep = (size_t)32 * TOTALW;
  const size_t bStep = (size_t)32 * w;
  const int lane = tid & 63;
  const int wid  = tid >> 6;
  const int wr = (wid >> 1) << 6;
  const int wc = (wid & 1) << 6;
  const int fr = lane & 15;
  const int kq = lane >> 4;
  f32x4v acc[4][4] = {};
  f32x4 av[4][2], bv[4][2];
  const int nk = w >> 6;
  {
    const float* a = ap; const float* b = bp;
#pragma unroll
    for (int i = 0; i < 4; ++i) {
      av[i][0] = *(const f32x4*)(a); av[i][1] = *(const f32x4*)(a + 4); a += aStep;
      bv[i][0] = *(const f32x4*)(b); bv[i][1] = *(const f32x4*)(b + 4); b += bStep;
    }
  }
  for (int kt = 0; kt < nk; ++kt) {
#pragma unroll
    for (int i = 0; i < 4; ++i) {
      const int row = srow + 32 * i;
      const int e = (row * 64 + sk) ^ ((row & 7) << 3);
      *(bf16x8*)&Asf[e] = cvt8(av[i][0], av[i][1]);
      *(bf16x8*)&Bsf[e] = cvt8(bv[i][0], bv[i][1]);
    }
    __syncthreads();
    if (kt + 1 < nk) {
      const float* a = ap + (kt + 1) * 64;
      const float* b = bp + (kt + 1) * 64;
#pragma unroll
      for (int i = 0; i < 4; ++i) {
        av[i][0] = *(const f32x4*)(a); av[i][1] = *(const f32x4*)(a + 4); a += aStep;
        bv[i][0] = *(const f32x4*)(b); bv[i][1] = *(const f32x4*)(b + 4); b += bStep;
      }
    }
#pragma unroll
    for (int kk = 0; kk < 2; ++kk) {
      const int kb = kk * 32 + kq * 8;
      bf16x8 afr[4], bfr[4];
#pragma unroll
      for (int i = 0; i < 4; ++i) {
        const int ra = wr + i * 16 + fr;
        afr[i] = *(const bf16x8*)&Asf[(ra * 64 + kb) ^ ((fr & 7) << 3)];
        const int rb = wc + i * 16 + fr;
        bfr[i] = *(const bf16x8*)&Bsf[(rb * 64 + kb) ^ ((fr & 7) << 3)];
      }
#pragma unroll
      for (int mi = 0; mi < 4; ++mi)
#pragma unroll
        for (int ni = 0; ni < 4; ++ni)
          acc[mi][ni] = __builtin_amdgcn_mfma_f32_16x16x32_bf16(afr[mi], bfr[ni], acc[mi][ni], 0, 0, 0);
    }
    __syncthreads();
  }
  float* op = args.out + (size_t)(mt * 128 + wr + kq * 4) * TOTALW + (c << 7) + wc + fr;
#pragma unroll
  for (int mi = 0; mi < 4; ++mi) {
#pragma unroll
    for (int ni = 0; ni < 4; ++ni) {
      float* pq = op + (size_t)(mi * 16) * TOTALW + ni * 16;
      pq[0 * TOTALW] = acc[mi][ni][0];
      pq[1 * TOTALW] = acc[mi][ni][1];
      pq[2 * TOTALW] = acc[mi][ni][2];
      pq[3 * TOTALW] = acc[mi][ni][3];
    }
  }
}

extern "C" void kernel_launch(void* const* d_in, const int* in_sizes, int n_in,
                              void* d_out, int out_size, void* d_ws, size_t ws_size,
                              hipStream_t stream) {
  if (ws_size >= WTOT * 2) {
    WCArgs wa;
    for (int i = 0; i < 8; ++i) wa.W[i] = (const float*)d_in[1 + i];
    wa.ws = (ushort*)d_ws;
    wconvert_kernel<<<1344, 256, 0, stream>>>(wa);   // 1344*256*8 == WTOT

    GArgs ga;
    ga.x = (const float*)d_in[0];
    static const size_t cumW[8] = {0, 16384, 32768, 180224, 327680, 737280, 1146880, 1949696};
    for (int i = 0; i < 8; ++i) ga.Wb[i] = (const ushort*)d_ws + cumW[i];
    ga.out = (float*)d_out;
    gemm_kernel<<<5120, 512, 0, stream>>>(ga);
  } else {
    FArgs fa;
    fa.x = (const float*)d_in[0];
    for (int i = 0; i < 8; ++i) fa.W[i] = (const float*)d_in[1 + i];
    fa.out = (float*)d_out;
    ielin_fb<<<8192, 256, 0, stream>>>(fa);
  }
}

// Round 16
// 462.869 us; speedup vs baseline: 5.5233x; 5.5233x over previous
//
#include <hip/hip_runtime.h>

typedef __attribute__((ext_vector_type(4))) float f32x4;
typedef __attribute__((ext_vector_type(8))) __bf16 bf16x8;
typedef __attribute__((ext_vector_type(4))) float f32x4v;

#define TOTALW 4096
static const size_t WTOT = 2752512ull;           // sum w^2

__device__ __forceinline__ bf16x8 cvt8(f32x4 a, f32x4 b) {
  bf16x8 r;
  r[0] = (__bf16)a.x; r[1] = (__bf16)a.y; r[2] = (__bf16)a.z; r[3] = (__bf16)a.w;
  r[4] = (__bf16)b.x; r[5] = (__bf16)b.y; r[6] = (__bf16)b.z; r[7] = (__bf16)b.w;
  return r;
}

// ---------------- pass 1: fp32 -> bf16 convert of W only (5.5 MB, ~10us) ----------------
struct WCArgs { const float* W[8]; ushort* ws; };

__global__ __launch_bounds__(256) void wconvert_kernel(WCArgs a) {
  const size_t e = ((size_t)blockIdx.x * 256 + threadIdx.x) << 3;
  if (e >= WTOT) return;
  int l = 0; size_t base = 0;
  if (e >= 16384)   { l = 1; base = 16384; }
  if (e >= 32768)   { l = 2; base = 32768; }
  if (e >= 180224)  { l = 3; base = 180224; }
  if (e >= 327680)  { l = 4; base = 327680; }
  if (e >= 737280)  { l = 5; base = 737280; }
  if (e >= 1146880) { l = 6; base = 1146880; }
  if (e >= 1949696) { l = 7; base = 1949696; }
  const float* w = a.W[0];
  if (l == 1) w = a.W[1]; if (l == 2) w = a.W[2]; if (l == 3) w = a.W[3];
  if (l == 4) w = a.W[4]; if (l == 5) w = a.W[5]; if (l == 6) w = a.W[6];
  if (l == 7) w = a.W[7];
  const float* src = w + (e - base);
  f32x4 v0 = *(const f32x4*)src;
  f32x4 v1 = *(const f32x4*)(src + 4);
  *(bf16x8*)(a.ws + e) = cvt8(v0, v1);
}

// ---------------- pass 2: fused GEMM, r14 structure + A reg-double-buffer ----------------
// r15 retried with the ONLY change: launch_bounds (512,6) -> (512,2). r15's bound
// forced VGPR to 40 and spilled 10 GB (r2's mistake repeated). VGPR floats (~80-96),
// LDS 48KB still gives 3 blocks/CU naturally (r14 evidence).
struct GArgs { const float* x; const ushort* Wb[8]; float* out; };

__device__ __forceinline__ void gl16(const ushort* g, ushort* l) {
  __builtin_amdgcn_global_load_lds(
      (const __attribute__((address_space(1))) void*)g,
      (__attribute__((address_space(3))) void*)l, 16, 0, 0);
}

#define VMW(n) asm volatile("s_waitcnt vmcnt(" #n ")" ::: "memory")

__global__ __launch_bounds__(512, 2) void gemm_kernel(GArgs args) {
  __shared__ __align__(16) ushort As[128 * 64];   // 16 KB (ds_write, XOR-swizzled dest)
  __shared__ __align__(16) ushort Bs[256 * 64];   // 32 KB (gl16 linear dest, src pre-XOR)

  const int tid = threadIdx.x;
  const int bid = blockIdx.x;
  const int work = (bid & 7) * 640 + (bid >> 3);   // XCD-chunked, mt-major
  const int mt = work / 20;
  const int t  = 19 - (work - mt * 20);            // heavy-first

  const int l = (t >= 1) + (t >= 2) + (t >= 4) + (t >= 6) + (t >= 9) + (t >= 12) + (t >= 16);
  const int p = l >> 1, q = l & 1;
  const int nirr = l | 1;                          // {1,1,3,3,5,5,7,7}
  const int cstart = 2 * p * p + q * nirr;
  const int w  = nirr << 7;                        // K
  const int nk = nirr << 1;                        // K-tiles of 64 (always even)
  const int sK = cstart << 7;
  const int tstart = (p + q) * (p + 1);
  const int j = t - tstart;
  const bool tail = (j == p);                      // last tile 128 wide
  const int col  = sK + j * 256;
  const ushort* __restrict__ Wbl = args.Wb[l];

  // B staging (gl16): linear LDS dest, source chunk pre-XORed (rule 21)
  const int trow = tid >> 3;                       // 0..63
  const int schunk = (tid & 7) ^ (trow & 7);
  const ushort* bSrc = Wbl + (size_t)(j * 256 + trow) * w + schunk * 8;

  // A staging (fp32 regs -> cvt -> swizzled ds_write)
  const int arow = tid >> 3;
  const int ask  = (tid & 7) << 3;
  const float* __restrict__ aSrc0 = args.x + (size_t)(mt * 128 + arow) * TOTALW + sK + ask;
  const float* __restrict__ aSrc1 = aSrc0 + (size_t)64 * TOTALW;
  ushort* aDst0 = &As[((arow     ) * 64 + ask) ^ ((arow & 7) << 3)];
  ushort* aDst1 = &As[((arow + 64) * 64 + ask) ^ ((arow & 7) << 3)];   // (arow+64)&7 == arow&7

  const int lane = tid & 63;
  const int wid  = tid >> 6;
  const int fr = lane & 15;
  const int kq = lane >> 4;

#define SHB(kt, r) gl16(bSrc + (size_t)((r) * 64) * w + (size_t)(kt) * 64, &Bs[(r) * 4096 + tid * 8])
#define ALD(n0, n1, n2, n3, k)                              \
  { n0 = *(const f32x4*)(aSrc0 + (k) * 64);                 \
    n1 = *(const f32x4*)(aSrc0 + (k) * 64 + 4);             \
    n2 = *(const f32x4*)(aSrc1 + (k) * 64);                 \
    n3 = *(const f32x4*)(aSrc1 + (k) * 64 + 4); }

  if (!tail) {
    // ---- 128x256 tile: 2x4 wave grid, wave tile 64x64 ----
    const int wr = (wid >> 2) << 6;
    const int wc = (wid & 3) << 6;
    f32x4v acc[4][4] = {};
    f32x4 pa0, pa1, pa2, pa3, qa0, qa1, qa2, qa3;

// steady state at body entry: A(k) 4 loads in flight (issued prev body, youngest).
// issue B(k) [oldest-after-A], then A(k+1); vmcnt(8) retires A(k) -> cvt+ds_write;
// vmcnt(4) retires B(k); A(k+1) stays in flight across MFMA.
#define BODYM(c0, c1, c2, c3, n0, n1, n2, n3, k)                         \
  {                                                                      \
    SHB(k, 0); SHB(k, 1); SHB(k, 2); SHB(k, 3);                          \
    __builtin_amdgcn_sched_barrier(0);                                   \
    if ((k) + 1 < nk) {                                                  \
      ALD(n0, n1, n2, n3, (k) + 1);                                      \
      __builtin_amdgcn_sched_barrier(0);                                 \
      VMW(8);                                                            \
    } else { VMW(4); }                                                   \
    *(bf16x8*)aDst0 = cvt8(c0, c1);                                      \
    *(bf16x8*)aDst1 = cvt8(c2, c3);                                      \
    __builtin_amdgcn_sched_barrier(0);                                   \
    if ((k) + 1 < nk) { VMW(4); } else { VMW(0); }                       \
    asm volatile("s_waitcnt lgkmcnt(0)" ::: "memory");                   \
    __syncthreads();                                                     \
    _Pragma("unroll")                                                    \
    for (int kk = 0; kk < 2; ++kk) {                                     \
      const int kb = kk * 32 + kq * 8;                                   \
      bf16x8 afr[4], bfr[4];                                             \
      _Pragma("unroll")                                                  \
      for (int i = 0; i < 4; ++i) {                                      \
        const int ra = wr + i * 16 + fr;                                 \
        afr[i] = *(const bf16x8*)&As[(ra * 64 + kb) ^ ((fr & 7) << 3)];  \
        const int rb = wc + i * 16 + fr;                                 \
        bfr[i] = *(const bf16x8*)&Bs[(rb * 64 + kb) ^ ((fr & 7) << 3)];  \
      }                                                                  \
      _Pragma("unroll")                                                  \
      for (int mi = 0; mi < 4; ++mi)                                     \
        _Pragma("unroll")                                                \
        for (int ni = 0; ni < 4; ++ni)                                   \
          acc[mi][ni] = __builtin_amdgcn_mfma_f32_16x16x32_bf16(afr[mi], bfr[ni], acc[mi][ni], 0, 0, 0); \
    }                                                                    \
    if ((k) + 1 < nk) __syncthreads();                                   \
  }

    ALD(pa0, pa1, pa2, pa3, 0);                     // prologue: A(0) in flight
    for (int kt = 0; kt < nk; kt += 2) {
      BODYM(pa0, pa1, pa2, pa3, qa0, qa1, qa2, qa3, kt);
      BODYM(qa0, qa1, qa2, qa3, pa0, pa1, pa2, pa3, kt + 1);
    }
#undef BODYM

    float* op = args.out + (size_t)(mt * 128 + wr + kq * 4) * TOTALW + col + wc + fr;
#pragma unroll
    for (int mi = 0; mi < 4; ++mi) {
#pragma unroll
      for (int ni = 0; ni < 4; ++ni) {
        float* pp = op + (size_t)(mi * 16) * TOTALW + ni * 16;
        pp[0 * TOTALW] = acc[mi][ni][0];
        pp[1 * TOTALW] = acc[mi][ni][1];
        pp[2 * TOTALW] = acc[mi][ni][2];
        pp[3 * TOTALW] = acc[mi][ni][3];
      }
    }
  } else {
    // ---- 128x128 tail tile: 4x2 wave grid, wave tile 32x64 ----
    const int wr = (wid >> 1) << 5;
    const int wc = (wid & 1) << 6;
    f32x4v acc[2][4] = {};
    f32x4 pa0, pa1, pa2, pa3, qa0, qa1, qa2, qa3;

#define BODYT(c0, c1, c2, c3, n0, n1, n2, n3, k)                         \
  {                                                                      \
    SHB(k, 0); SHB(k, 1);                                                \
    __builtin_amdgcn_sched_barrier(0);                                   \
    if ((k) + 1 < nk) {                                                  \
      ALD(n0, n1, n2, n3, (k) + 1);                                      \
      __builtin_amdgcn_sched_barrier(0);                                 \
      VMW(6);                                                            \
    } else { VMW(2); }                                                   \
    *(bf16x8*)aDst0 = cvt8(c0, c1);                                      \
    *(bf16x8*)aDst1 = cvt8(c2, c3);                                      \
    __builtin_amdgcn_sched_barrier(0);                                   \
    if ((k) + 1 < nk) { VMW(4); } else { VMW(0); }                       \
    asm volatile("s_waitcnt lgkmcnt(0)" ::: "memory");                   \
    __syncthreads();                                                     \
    _Pragma("unroll")                                                    \
    for (int kk = 0; kk < 2; ++kk) {                                     \
      const int kb = kk * 32 + kq * 8;                                   \
      bf16x8 afr[2], bfr[4];                                             \
      _Pragma("unroll")                                                  \
      for (int i = 0; i < 2; ++i) {                                      \
        const int ra = wr + i * 16 + fr;                                 \
        afr[i] = *(const bf16x8*)&As[(ra * 64 + kb) ^ ((fr & 7) << 3)];  \
      }                                                                  \
      _Pragma("unroll")                                                  \
      for (int i = 0; i < 4; ++i) {                                      \
        const int rb = wc + i * 16 + fr;                                 \
        bfr[i] = *(const bf16x8*)&Bs[(rb * 64 + kb) ^ ((fr & 7) << 3)];  \
      }                                                                  \
      _Pragma("unroll")                                                  \
      for (int mi = 0; mi < 2; ++mi)                                     \
        _Pragma("unroll")                                                \
        for (int ni = 0; ni < 4; ++ni)                                   \
          acc[mi][ni] = __builtin_amdgcn_mfma_f32_16x16x32_bf16(afr[mi], bfr[ni], acc[mi][ni], 0, 0, 0); \
    }                                                                    \
    if ((k) + 1 < nk) __syncthreads();                                   \
  }

    ALD(pa0, pa1, pa2, pa3, 0);
    for (int kt = 0; kt < nk; kt += 2) {
      BODYT(pa0, pa1, pa2, pa3, qa0, qa1, qa2, qa3, kt);
      BODYT(qa0, qa1, qa2, qa3, pa0, pa1, pa2, pa3, kt + 1);
    }
#undef BODYT

    float* op = args.out + (size_t)(mt * 128 + wr + kq * 4) * TOTALW + col + wc + fr;
#pragma unroll
    for (int mi = 0; mi < 2; ++mi) {
#pragma unroll
      for (int ni = 0; ni < 4; ++ni) {
        float* pp = op + (size_t)(mi * 16) * TOTALW + ni * 16;
        pp[0 * TOTALW] = acc[mi][ni][0];
        pp[1 * TOTALW] = acc[mi][ni][1];
        pp[2 * TOTALW] = acc[mi][ni][2];
        pp[3 * TOTALW] = acc[mi][ni][3];
      }
    }
  }
#undef SHB
#undef ALD
}

// ---------------- fallback (round-1 kernel, used only if ws too small) ----------------
struct FArgs { const float* x; const float* W[8]; float* out; };

__global__ __launch_bounds__(256, 2) void ielin_fb(FArgs args) {
  __shared__ __align__(16) ushort Asf[128 * 64];
  __shared__ __align__(16) ushort Bsf[128 * 64];
  const int tid = threadIdx.x;
  const int bid = blockIdx.x;
  const int work = (bid & 7) * 1024 + (bid >> 3);
  const int mt = work >> 5;
  const int c  = work & 31;
  const int l = (c >= 1) + (c >= 2) + (c >= 5) + (c >= 8) + (c >= 13) + (c >= 18) + (c >= 25);
  const int pp = l >> 1, qq = l & 1;
  const int nirr = l | 1;
  const int cstart = 2 * pp * pp + qq * nirr;
  const int w  = nirr << 7;
  const int sK = cstart << 7;
  const int noff = (c - cstart) << 7;
  const float* __restrict__ Wl = args.W[l];
  const int srow = tid >> 3;
  const int sk   = (tid & 7) << 3;
  const float* ap = args.x + (size_t)(mt * 128 + srow) * TOTALW + sK + sk;
  const float* bp = Wl + (size_t)(noff + srow) * w + sk;
  const size_t aStep = (size_t)32 * TOTALW;
  const size_t bStep = (size_t)32 * w;
  const int lane = tid & 63;
  const int wid  = tid >> 6;
  const int wr = (wid >> 1) << 6;
  const int wc = (wid & 1) << 6;
  const int fr = lane & 15;
  const int kq = lane >> 4;
  f32x4v acc[4][4] = {};
  f32x4 av[4][2], bv[4][2];
  const int nk = w >> 6;
  {
    const float* a = ap; const float* b = bp;
#pragma unroll
    for (int i = 0; i < 4; ++i) {
      av[i][0] = *(const f32x4*)(a); av[i][1] = *(const f32x4*)(a + 4); a += aStep;
      bv[i][0] = *(const f32x4*)(b); bv[i][1] = *(const f32x4*)(b + 4); b += bStep;
    }
  }
  for (int kt = 0; kt < nk; ++kt) {
#pragma unroll
    for (int i = 0; i < 4; ++i) {
      const int row = srow + 32 * i;
      const int e = (row * 64 + sk) ^ ((row & 7) << 3);
      *(bf16x8*)&Asf[e] = cvt8(av[i][0], av[i][1]);
      *(bf16x8*)&Bsf[e] = cvt8(bv[i][0], bv[i][1]);
    }
    __syncthreads();
    if (kt + 1 < nk) {
      const float* a = ap + (kt + 1) * 64;
      const float* b = bp + (kt + 1) * 64;
#pragma unroll
      for (int i = 0; i < 4; ++i) {
        av[i][0] = *(const f32x4*)(a); av[i][1] = *(const f32x4*)(a + 4); a += aStep;
        bv[i][0] = *(const f32x4*)(b); bv[i][1] = *(const f32x4*)(b + 4); b += bStep;
      }
    }
#pragma unroll
    for (int kk = 0; kk < 2; ++kk) {
      const int kb = kk * 32 + kq * 8;
      bf16x8 afr[4], bfr[4];
#pragma unroll
      for (int i = 0; i < 4; ++i) {
        const int ra = wr + i * 16 + fr;
        afr[i] = *(const bf16x8*)&Asf[(ra * 64 + kb) ^ ((fr & 7) << 3)];
        const int rb = wc + i * 16 + fr;
        bfr[i] = *(const bf16x8*)&Bsf[(rb * 64 + kb) ^ ((fr & 7) << 3)];
      }
#pragma unroll
      for (int mi = 0; mi < 4; ++mi)
#pragma unroll
        for (int ni = 0; ni < 4; ++ni)
          acc[mi][ni] = __builtin_amdgcn_mfma_f32_16x16x32_bf16(afr[mi], bfr[ni], acc[mi][ni], 0, 0, 0);
    }
    __syncthreads();
  }
  float* op = args.out + (size_t)(mt * 128 + wr + kq * 4) * TOTALW + (c << 7) + wc + fr;
#pragma unroll
  for (int mi = 0; mi < 4; ++mi) {
#pragma unroll
    for (int ni = 0; ni < 4; ++ni) {
      float* pq = op + (size_t)(mi * 16) * TOTALW + ni * 16;
      pq[0 * TOTALW] = acc[mi][ni][0];
      pq[1 * TOTALW] = acc[mi][ni][1];
      pq[2 * TOTALW] = acc[mi][ni][2];
      pq[3 * TOTALW] = acc[mi][ni][3];
    }
  }
}

extern "C" void kernel_launch(void* const* d_in, const int* in_sizes, int n_in,
                              void* d_out, int out_size, void* d_ws, size_t ws_size,
                              hipStream_t stream) {
  if (ws_size >= WTOT * 2) {
    WCArgs wa;
    for (int i = 0; i < 8; ++i) wa.W[i] = (const float*)d_in[1 + i];
    wa.ws = (ushort*)d_ws;
    wconvert_kernel<<<1344, 256, 0, stream>>>(wa);   // 1344*256*8 == WTOT

    GArgs ga;
    ga.x = (const float*)d_in[0];
    static const size_t cumW[8] = {0, 16384, 32768, 180224, 327680, 737280, 1146880, 1949696};
    for (int i = 0; i < 8; ++i) ga.Wb[i] = (const ushort*)d_ws + cumW[i];
    ga.out = (float*)d_out;
    gemm_kernel<<<5120, 512, 0, stream>>>(ga);
  } else {
    FArgs fa;
    fa.x = (const float*)d_in[0];
    for (int i = 0; i < 8; ++i) fa.W[i] = (const float*)d_in[1 + i];
    fa.out = (float*)d_out;
    ielin_fb<<<8192, 256, 0, stream>>>(fa);
  }
}

// Round 17
// 373.061 us; speedup vs baseline: 6.8529x; 1.2407x over previous
//
#include <hip/hip_runtime.h>

typedef __attribute__((ext_vector_type(4))) float f32x4;
typedef __attribute__((ext_vector_type(8))) __bf16 bf16x8;
typedef __attribute__((ext_vector_type(4))) float f32x4v;

#define TOTALW 4096
static const size_t WTOT = 2752512ull;           // sum w^2

__device__ __forceinline__ bf16x8 cvt8(f32x4 a, f32x4 b) {
  bf16x8 r;
  r[0] = (__bf16)a.x; r[1] = (__bf16)a.y; r[2] = (__bf16)a.z; r[3] = (__bf16)a.w;
  r[4] = (__bf16)b.x; r[5] = (__bf16)b.y; r[6] = (__bf16)b.z; r[7] = (__bf16)b.w;
  return r;
}

// ---------------- pass 1: fp32 -> bf16 convert of W only (5.5 MB, ~10us) ----------------
struct WCArgs { const float* W[8]; ushort* ws; };

__global__ __launch_bounds__(256) void wconvert_kernel(WCArgs a) {
  const size_t e = ((size_t)blockIdx.x * 256 + threadIdx.x) << 3;
  if (e >= WTOT) return;
  int l = 0; size_t base = 0;
  if (e >= 16384)   { l = 1; base = 16384; }
  if (e >= 32768)   { l = 2; base = 32768; }
  if (e >= 180224)  { l = 3; base = 180224; }
  if (e >= 327680)  { l = 4; base = 327680; }
  if (e >= 737280)  { l = 5; base = 737280; }
  if (e >= 1146880) { l = 6; base = 1146880; }
  if (e >= 1949696) { l = 7; base = 1949696; }
  const float* w = a.W[0];
  if (l == 1) w = a.W[1]; if (l == 2) w = a.W[2]; if (l == 3) w = a.W[3];
  if (l == 4) w = a.W[4]; if (l == 5) w = a.W[5]; if (l == 6) w = a.W[6];
  if (l == 7) w = a.W[7];
  const float* src = w + (e - base);
  f32x4 v0 = *(const f32x4*)src;
  f32x4 v1 = *(const f32x4*)(src + 4);
  *(bf16x8*)(a.ws + e) = cvt8(v0, v1);
}

// ---------------- pass 2: fused GEMM (r14-exact structure + T5 setprio) ----------------
// r14 = best measured (gemm 387us, 3 blocks/CU, VGPR 64). ONLY change vs r14:
// s_setprio(1)/(0) around the MFMA cluster. The 3 resident blocks are phase-
// independent -> role-split exists (staging waves vs MFMA waves) -> scheduler can
// favor compute-phase waves (T5 prerequisite per m191/m218b; m190's null was a
// lockstep structure). Zero resource cost: no VGPR/LDS/sync change.
struct GArgs { const float* x; const ushort* Wb[8]; float* out; };

__device__ __forceinline__ void gl16(const ushort* g, ushort* l) {
  __builtin_amdgcn_global_load_lds(
      (const __attribute__((address_space(1))) void*)g,
      (__attribute__((address_space(3))) void*)l, 16, 0, 0);
}

#define VMW(n) asm volatile("s_waitcnt vmcnt(" #n ")" ::: "memory")

__global__ __launch_bounds__(512, 2) void gemm_kernel(GArgs args) {
  __shared__ __align__(16) ushort As[128 * 64];   // 16 KB (ds_write, XOR-swizzled dest)
  __shared__ __align__(16) ushort Bs[256 * 64];   // 32 KB (gl16 linear dest, src pre-XOR)

  const int tid = threadIdx.x;
  const int bid = blockIdx.x;
  const int work = (bid & 7) * 640 + (bid >> 3);   // XCD-chunked, mt-major
  const int mt = work / 20;
  const int t  = 19 - (work - mt * 20);            // heavy-first

  const int l = (t >= 1) + (t >= 2) + (t >= 4) + (t >= 6) + (t >= 9) + (t >= 12) + (t >= 16);
  const int p = l >> 1, q = l & 1;
  const int nirr = l | 1;                          // {1,1,3,3,5,5,7,7}
  const int cstart = 2 * p * p + q * nirr;
  const int w  = nirr << 7;                        // K
  const int nk = nirr << 1;                        // K-tiles of 64
  const int sK = cstart << 7;
  const int tstart = (p + q) * (p + 1);
  const int j = t - tstart;
  const bool tail = (j == p);                      // last tile 128 wide
  const int col  = sK + j * 256;
  const ushort* __restrict__ Wbl = args.Wb[l];

  // B staging (gl16): linear LDS dest, source chunk pre-XORed (rule 21)
  const int trow = tid >> 3;                       // 0..63
  const int schunk = (tid & 7) ^ (trow & 7);
  const ushort* bSrc = Wbl + (size_t)(j * 256 + trow) * w + schunk * 8;

  // A staging (fp32 regs -> cvt -> swizzled ds_write)
  const int arow = tid >> 3;
  const int ask  = (tid & 7) << 3;
  const float* __restrict__ aSrc0 = args.x + (size_t)(mt * 128 + arow) * TOTALW + sK + ask;
  const float* __restrict__ aSrc1 = aSrc0 + (size_t)64 * TOTALW;
  ushort* aDst0 = &As[((arow     ) * 64 + ask) ^ ((arow & 7) << 3)];
  ushort* aDst1 = &As[((arow + 64) * 64 + ask) ^ ((arow & 7) << 3)];   // (arow+64)&7 == arow&7

  const int lane = tid & 63;
  const int wid  = tid >> 6;
  const int fr = lane & 15;
  const int kq = lane >> 4;

#define SHB(kt, r) gl16(bSrc + (size_t)((r) * 64) * w + (size_t)(kt) * 64, &Bs[(r) * 4096 + tid * 8])

  if (!tail) {
    // ---- 128x256 tile: 2x4 wave grid, wave tile 64x64 ----
    const int wr = (wid >> 2) << 6;
    const int wc = (wid & 3) << 6;
    f32x4v acc[4][4] = {};

    for (int kt = 0; kt < nk; ++kt) {
      // A fp32 loads first (oldest in vmcnt queue)
      f32x4 a0 = *(const f32x4*)(aSrc0 + kt * 64);
      f32x4 a1 = *(const f32x4*)(aSrc0 + kt * 64 + 4);
      f32x4 a2 = *(const f32x4*)(aSrc1 + kt * 64);
      f32x4 a3 = *(const f32x4*)(aSrc1 + kt * 64 + 4);
      __builtin_amdgcn_sched_barrier(0);
      SHB(kt, 0); SHB(kt, 1); SHB(kt, 2); SHB(kt, 3);
      __builtin_amdgcn_sched_barrier(0);
      // wait A only (4 B-gl16 still in flight), convert+write to LDS
      asm volatile("s_waitcnt vmcnt(4)" ::: "memory");
      *(bf16x8*)aDst0 = cvt8(a0, a1);
      *(bf16x8*)aDst1 = cvt8(a2, a3);
      __builtin_amdgcn_sched_barrier(0);
      asm volatile("s_waitcnt vmcnt(0) lgkmcnt(0)" ::: "memory");
      __syncthreads();

      __builtin_amdgcn_s_setprio(1);
#pragma unroll
      for (int kk = 0; kk < 2; ++kk) {
        const int kb = kk * 32 + kq * 8;
        bf16x8 afr[4], bfr[4];
#pragma unroll
        for (int i = 0; i < 4; ++i) {
          const int ra = wr + i * 16 + fr;          // ra&7 == fr&7
          afr[i] = *(const bf16x8*)&As[(ra * 64 + kb) ^ ((fr & 7) << 3)];
          const int rb = wc + i * 16 + fr;
          bfr[i] = *(const bf16x8*)&Bs[(rb * 64 + kb) ^ ((fr & 7) << 3)];
        }
#pragma unroll
        for (int mi = 0; mi < 4; ++mi)
#pragma unroll
          for (int ni = 0; ni < 4; ++ni)
            acc[mi][ni] = __builtin_amdgcn_mfma_f32_16x16x32_bf16(afr[mi], bfr[ni], acc[mi][ni], 0, 0, 0);
      }
      __builtin_amdgcn_s_setprio(0);
      if (kt + 1 < nk) __syncthreads();
    }

    float* op = args.out + (size_t)(mt * 128 + wr + kq * 4) * TOTALW + col + wc + fr;
#pragma unroll
    for (int mi = 0; mi < 4; ++mi) {
#pragma unroll
      for (int ni = 0; ni < 4; ++ni) {
        float* pp = op + (size_t)(mi * 16) * TOTALW + ni * 16;
        pp[0 * TOTALW] = acc[mi][ni][0];
        pp[1 * TOTALW] = acc[mi][ni][1];
        pp[2 * TOTALW] = acc[mi][ni][2];
        pp[3 * TOTALW] = acc[mi][ni][3];
      }
    }
  } else {
    // ---- 128x128 tail tile: 4x2 wave grid, wave tile 32x64 ----
    const int wr = (wid >> 1) << 5;
    const int wc = (wid & 1) << 6;
    f32x4v acc[2][4] = {};

    for (int kt = 0; kt < nk; ++kt) {
      f32x4 a0 = *(const f32x4*)(aSrc0 + kt * 64);
      f32x4 a1 = *(const f32x4*)(aSrc0 + kt * 64 + 4);
      f32x4 a2 = *(const f32x4*)(aSrc1 + kt * 64);
      f32x4 a3 = *(const f32x4*)(aSrc1 + kt * 64 + 4);
      __builtin_amdgcn_sched_barrier(0);
      SHB(kt, 0); SHB(kt, 1);
      __builtin_amdgcn_sched_barrier(0);
      asm volatile("s_waitcnt vmcnt(2)" ::: "memory");   // A done, 2 B-gl16 in flight
      *(bf16x8*)aDst0 = cvt8(a0, a1);
      *(bf16x8*)aDst1 = cvt8(a2, a3);
      __builtin_amdgcn_sched_barrier(0);
      asm volatile("s_waitcnt vmcnt(0) lgkmcnt(0)" ::: "memory");
      __syncthreads();

      __builtin_amdgcn_s_setprio(1);
#pragma unroll
      for (int kk = 0; kk < 2; ++kk) {
        const int kb = kk * 32 + kq * 8;
        bf16x8 afr[2], bfr[4];
#pragma unroll
        for (int i = 0; i < 2; ++i) {
          const int ra = wr + i * 16 + fr;
          afr[i] = *(const bf16x8*)&As[(ra * 64 + kb) ^ ((fr & 7) << 3)];
        }
#pragma unroll
        for (int i = 0; i < 4; ++i) {
          const int rb = wc + i * 16 + fr;
          bfr[i] = *(const bf16x8*)&Bs[(rb * 64 + kb) ^ ((fr & 7) << 3)];
        }
#pragma unroll
        for (int mi = 0; mi < 2; ++mi)
#pragma unroll
          for (int ni = 0; ni < 4; ++ni)
            acc[mi][ni] = __builtin_amdgcn_mfma_f32_16x16x32_bf16(afr[mi], bfr[ni], acc[mi][ni], 0, 0, 0);
      }
      __builtin_amdgcn_s_setprio(0);
      if (kt + 1 < nk) __syncthreads();
    }

    float* op = args.out + (size_t)(mt * 128 + wr + kq * 4) * TOTALW + col + wc + fr;
#pragma unroll
    for (int mi = 0; mi < 2; ++mi) {
#pragma unroll
      for (int ni = 0; ni < 4; ++ni) {
        float* pp = op + (size_t)(mi * 16) * TOTALW + ni * 16;
        pp[0 * TOTALW] = acc[mi][ni][0];
        pp[1 * TOTALW] = acc[mi][ni][1];
        pp[2 * TOTALW] = acc[mi][ni][2];
        pp[3 * TOTALW] = acc[mi][ni][3];
      }
    }
  }
#undef SHB
}

// ---------------- fallback (round-1 kernel, used only if ws too small) ----------------
struct FArgs { const float* x; const float* W[8]; float* out; };

__global__ __launch_bounds__(256, 2) void ielin_fb(FArgs args) {
  __shared__ __align__(16) ushort Asf[128 * 64];
  __shared__ __align__(16) ushort Bsf[128 * 64];
  const int tid = threadIdx.x;
  const int bid = blockIdx.x;
  const int work = (bid & 7) * 1024 + (bid >> 3);
  const int mt = work >> 5;
  const int c  = work & 31;
  const int l = (c >= 1) + (c >= 2) + (c >= 5) + (c >= 8) + (c >= 13) + (c >= 18) + (c >= 25);
  const int pp = l >> 1, qq = l & 1;
  const int nirr = l | 1;
  const int cstart = 2 * pp * pp + qq * nirr;
  const int w  = nirr << 7;
  const int sK = cstart << 7;
  const int noff = (c - cstart) << 7;
  const float* __restrict__ Wl = args.W[l];
  const int srow = tid >> 3;
  const int sk   = (tid & 7) << 3;
  const float* ap = args.x + (size_t)(mt * 128 + srow) * TOTALW + sK + sk;
  const float* bp = Wl + (size_t)(noff + srow) * w + sk;
  const size_t aStep = (size_t)32 * TOTALW;
  const size_t bStep = (size_t)32 * w;
  const int lane = tid & 63;
  const int wid  = tid >> 6;
  const int wr = (wid >> 1) << 6;
  const int wc = (wid & 1) << 6;
  const int fr = lane & 15;
  const int kq = lane >> 4;
  f32x4v acc[4][4] = {};
  f32x4 av[4][2], bv[4][2];
  const int nk = w >> 6;
  {
    const float* a = ap; const float* b = bp;
#pragma unroll
    for (int i = 0; i < 4; ++i) {
      av[i][0] = *(const f32x4*)(a); av[i][1] = *(const f32x4*)(a + 4); a += aStep;
      bv[i][0] = *(const f32x4*)(b); bv[i][1] = *(const f32x4*)(b + 4); b += bStep;
    }
  }
  for (int kt = 0; kt < nk; ++kt) {
#pragma unroll
    for (int i = 0; i < 4; ++i) {
      const int row = srow + 32 * i;
      const int e = (row * 64 + sk) ^ ((row & 7) << 3);
      *(bf16x8*)&Asf[e] = cvt8(av[i][0], av[i][1]);
      *(bf16x8*)&Bsf[e] = cvt8(bv[i][0], bv[i][1]);
    }
    __syncthreads();
    if (kt + 1 < nk) {
      const float* a = ap + (kt + 1) * 64;
      const float* b = bp + (kt + 1) * 64;
#pragma unroll
      for (int i = 0; i < 4; ++i) {
        av[i][0] = *(const f32x4*)(a); av[i][1] = *(const f32x4*)(a + 4); a += aStep;
        bv[i][0] = *(const f32x4*)(b); bv[i][1] = *(const f32x4*)(b + 4); b += bStep;
      }
    }
#pragma unroll
    for (int kk = 0; kk < 2; ++kk) {
      const int kb = kk * 32 + kq * 8;
      bf16x8 afr[4], bfr[4];
#pragma unroll
      for (int i = 0; i < 4; ++i) {
        const int ra = wr + i * 16 + fr;
        afr[i] = *(const bf16x8*)&Asf[(ra * 64 + kb) ^ ((fr & 7) << 3)];
        const int rb = wc + i * 16 + fr;
        bfr[i] = *(const bf16x8*)&Bsf[(rb * 64 + kb) ^ ((fr & 7) << 3)];
      }
#pragma unroll
      for (int mi = 0; mi < 4; ++mi)
#pragma unroll
        for (int ni = 0; ni < 4; ++ni)
          acc[mi][ni] = __builtin_amdgcn_mfma_f32_16x16x32_bf16(afr[mi], bfr[ni], acc[mi][ni], 0, 0, 0);
    }
    __syncthreads();
  }
  float* op = args.out + (size_t)(mt * 128 + wr + kq * 4) * TOTALW + (c << 7) + wc + fr;
#pragma unroll
  for (int mi = 0; mi < 4; ++mi) {
#pragma unroll
    for (int ni = 0; ni < 4; ++ni) {
      float* pq = op + (size_t)(mi * 16) * TOTALW + ni * 16;
      pq[0 * TOTALW] = acc[mi][ni][0];
      pq[1 * TOTALW] = acc[mi][ni][1];
      pq[2 * TOTALW] = acc[mi][ni][2];
      pq[3 * TOTALW] = acc[mi][ni][3];
    }
  }
}

extern "C" void kernel_launch(void* const* d_in, const int* in_sizes, int n_in,
                              void* d_out, int out_size, void* d_ws, size_t ws_size,
                              hipStream_t stream) {
  if (ws_size >= WTOT * 2) {
    WCArgs wa;
    for (int i = 0; i < 8; ++i) wa.W[i] = (const float*)d_in[1 + i];
    wa.ws = (ushort*)d_ws;
    wconvert_kernel<<<1344, 256, 0, stream>>>(wa);   // 1344*256*8 == WTOT

    GArgs ga;
    ga.x = (const float*)d_in[0];
    static const size_t cumW[8] = {0, 16384, 32768, 180224, 327680, 737280, 1146880, 1949696};
    for (int i = 0; i < 8; ++i) ga.Wb[i] = (const ushort*)d_ws + cumW[i];
    ga.out = (float*)d_out;
    gemm_kernel<<<5120, 512, 0, stream>>>(ga);
  } else {
    FArgs fa;
    fa.x = (const float*)d_in[0];
    for (int i = 0; i < 8; ++i) fa.W[i] = (const float*)d_in[1 + i];
    fa.out = (float*)d_out;
    ielin_fb<<<8192, 256, 0, stream>>>(fa);
  }
}